// Round 10
// baseline (293.149 us; speedup 1.0000x reference)
//
#include <hip/hip_runtime.h>

#define HIDDEN 1024
#define NHEADS 16
#define HDIM 64
#define WINDOW 256
#define SEQ 2048
#define BATCH 2
#define MTOK (BATCH * SEQ)
#define LN_EPS 1e-12f

typedef _Float16 f16;
typedef _Float16 f16x4 __attribute__((ext_vector_type(4)));
typedef _Float16 f16x8 __attribute__((ext_vector_type(8)));
typedef float f32x4 __attribute__((ext_vector_type(4)));

// hi/lo split: x ~= hi + lo * 2^-11, lo scaled by 2^11 to stay in fp16 normal
// range (MFMA flushes fp16 denormals; weights ~0.03 would lose their lo).
__device__ inline void split_hl(float x, f16& h, f16& l) {
    const f16 hh = (f16)x;
    h = hh;
    l = (f16)((x - (float)hh) * 2048.0f);
}

// Direct global->LDS 16B async copy. LDS dest is WAVE-UNIFORM base; HW writes
// lane i's 16B at dest + i*16 (m104). Global src addr is per-lane (m173).
__device__ __forceinline__ void gload16(const f16* g, f16* l) {
    __builtin_amdgcn_global_load_lds(
        (const __attribute__((address_space(1))) void*)g,
        (__attribute__((address_space(3))) void*)l, 16, 0, 0);
}

// ---------------------------------------------------------------------------
// LayerNorm fused with hi/lo fp16 split output. One block per token row.
// ---------------------------------------------------------------------------
__global__ __launch_bounds__(256) void ln_split_kernel(const float* __restrict__ X,
                                                       const float* __restrict__ g,
                                                       const float* __restrict__ be,
                                                       f16* __restrict__ XH,
                                                       f16* __restrict__ XL) {
    const int row = blockIdx.x;
    const int t = threadIdx.x;
    const float4 v = ((const float4*)(X + (size_t)row * HIDDEN))[t];
    float s = v.x + v.y + v.z + v.w;
    float s2 = v.x * v.x + v.y * v.y + v.z * v.z + v.w * v.w;
#pragma unroll
    for (int off = 1; off < 64; off <<= 1) {
        s += __shfl_xor(s, off);
        s2 += __shfl_xor(s2, off);
    }
    __shared__ float ss[4], ss2[4];
    if ((t & 63) == 0) { ss[t >> 6] = s; ss2[t >> 6] = s2; }
    __syncthreads();
    s = ss[0] + ss[1] + ss[2] + ss[3];
    s2 = ss2[0] + ss2[1] + ss2[2] + ss2[3];
    const float mu = s * (1.f / HIDDEN);
    const float var = s2 * (1.f / HIDDEN) - mu * mu;
    const float rstd = rsqrtf(var + LN_EPS);
    const float4 gv = ((const float4*)g)[t];
    const float4 bv = ((const float4*)be)[t];
    float ov[4];
    ov[0] = (v.x - mu) * rstd * gv.x + bv.x;
    ov[1] = (v.y - mu) * rstd * gv.y + bv.y;
    ov[2] = (v.z - mu) * rstd * gv.z + bv.z;
    ov[3] = (v.w - mu) * rstd * gv.w + bv.w;
    f16x4 h, l;
#pragma unroll
    for (int j = 0; j < 4; ++j) { f16 hh, ll; split_hl(ov[j], hh, ll); h[j] = hh; l[j] = ll; }
    ((f16x4*)(XH + (size_t)row * HIDDEN))[t] = h;
    ((f16x4*)(XL + (size_t)row * HIDDEN))[t] = l;
}

// ---------------------------------------------------------------------------
// All-4-weights f32 -> fp16 hi/lo split in one launch (blockIdx.y = tensor).
// ---------------------------------------------------------------------------
__global__ __launch_bounds__(256) void wsplit_kernel(const float* __restrict__ W0,
                                                     const float* __restrict__ W1,
                                                     const float* __restrict__ W2,
                                                     const float* __restrict__ W3,
                                                     f16* __restrict__ H0, f16* __restrict__ L0,
                                                     f16* __restrict__ H1, f16* __restrict__ L1,
                                                     f16* __restrict__ H2, f16* __restrict__ L2,
                                                     f16* __restrict__ H3, f16* __restrict__ L3) {
    const float* X = (blockIdx.y == 0) ? W0 : (blockIdx.y == 1) ? W1 : (blockIdx.y == 2) ? W2 : W3;
    f16* H = (blockIdx.y == 0) ? H0 : (blockIdx.y == 1) ? H1 : (blockIdx.y == 2) ? H2 : H3;
    f16* L = (blockIdx.y == 0) ? L0 : (blockIdx.y == 1) ? L1 : (blockIdx.y == 2) ? L2 : L3;
    const int i = blockIdx.x * 256 + threadIdx.x;  // 8 elems per thread
    const float4 a = ((const float4*)X)[2 * i];
    const float4 b = ((const float4*)X)[2 * i + 1];
    const float xs[8] = {a.x, a.y, a.z, a.w, b.x, b.y, b.z, b.w};
    f16x8 h, l;
#pragma unroll
    for (int j = 0; j < 8; ++j) { f16 hh, ll; split_hl(xs[j], hh, ll); h[j] = hh; l[j] = ll; }
    ((f16x8*)H)[i] = h;
    ((f16x8*)L)[i] = l;
}

// ---------------------------------------------------------------------------
// GEMM staging: global_load_lds width-16 direct staging. Wave w stages one
// array (0=Ah,1=Al,2=Bh,3=Bl), 8x 1KB wave-loads per K-step. LDS layout is
// LINEAR [128][32] halfs (64B rows) with XOR swizzle slot' = slot^((row>>1)&3)
// applied on BOTH sides (rule 21): inverse-swizzled per-lane GLOBAL source +
// swizzled compute read. Per-8-lane phase covers all 32 banks exactly once
// => conflict-free ds_read_b128. Values and MFMA order bit-identical to the
// verified round-6 reg-staged kernel.
// ---------------------------------------------------------------------------

// ---------------------------------------------------------------------------
// FUSED Q/K/V hi/lo fp16 MFMA GEMM-NT. blockIdx.z selects weight/bias/output
// (Q, K -> [b,h,s,d]; V -> [b,h,d,s]).
// ---------------------------------------------------------------------------
__global__ __launch_bounds__(256, 2) void gemm_qkv(
        const f16* __restrict__ Ah_g, const f16* __restrict__ Al_g,
        const f16* __restrict__ Wh0, const f16* __restrict__ Wl0,
        const f16* __restrict__ Wh1, const f16* __restrict__ Wl1,
        const f16* __restrict__ Wh2, const f16* __restrict__ Wl2,
        const float* __restrict__ b0, const float* __restrict__ b1,
        const float* __restrict__ b2,
        f16* __restrict__ O0h, f16* __restrict__ O0l,
        f16* __restrict__ O1h, f16* __restrict__ O1l,
        f16* __restrict__ O2h, f16* __restrict__ O2l) {
    constexpr int K = HIDDEN;
    __shared__ __align__(16) f16 AhL[128 * 32], AlL[128 * 32];
    __shared__ __align__(16) f16 BhL[128 * 32], BlL[128 * 32];
    const int z = blockIdx.z;  // uniform across block
    const f16* __restrict__ Bh_g = (z == 0) ? Wh0 : (z == 1) ? Wh1 : Wh2;
    const f16* __restrict__ Bl_g = (z == 0) ? Wl0 : (z == 1) ? Wl1 : Wl2;
    const float* __restrict__ bias = (z == 0) ? b0 : (z == 1) ? b1 : b2;
    f16* __restrict__ OH = (z == 0) ? O0h : (z == 1) ? O1h : O2h;
    f16* __restrict__ OL = (z == 0) ? O0l : (z == 1) ? O1l : O2l;
    const int tid = threadIdx.x;
    const int m0 = blockIdx.x << 7, n0 = blockIdx.y << 7;
    const int w = tid >> 6, lane = tid & 63;
    const int wr = w >> 1, wc = w & 1;            // wave grid 2x2
    const int lr = lane & 15, lk = lane >> 4;     // frag row + k-group
    // staging role: wave w stages one array
    const f16* sg = (w == 0) ? Ah_g : (w == 1) ? Al_g : (w == 2) ? Bh_g : Bl_g;
    f16* sd = (w == 0) ? AhL : (w == 1) ? AlL : (w == 2) ? BhL : BlL;
    const int t0 = (w < 2) ? m0 : n0;
    const int srow = lane >> 2;                   // 0..15 row within 16-row chunk
    const int sslot = lane & 3;                   // 16B slot within 64B row
    const f32x4 zf = {0.f, 0.f, 0.f, 0.f};
    f32x4 acc1[4][4], acc2[4][4];
#pragma unroll
    for (int i = 0; i < 4; ++i)
#pragma unroll
        for (int j = 0; j < 4; ++j) { acc1[i][j] = zf; acc2[i][j] = zf; }

    for (int k0 = 0; k0 < K; k0 += 32) {
        __syncthreads();
#pragma unroll
        for (int q = 0; q < 8; ++q) {
            const int r = (q << 4) + srow;                 // tile row 0..127
            const int g = sslot ^ ((r >> 1) & 3);          // inverse swizzle on src
            gload16(sg + (size_t)(t0 + r) * K + k0 + (g << 3), sd + (q << 9));
        }
        __syncthreads();
        f16x8 bh[4], bl[4];
#pragma unroll
        for (int j = 0; j < 4; ++j) {
            const int Rb = (wc << 6) + (j << 4) + lr;
            const int sb = ((lk ^ ((Rb >> 1) & 3)) << 3);
            bh[j] = *(const f16x8*)&BhL[Rb * 32 + sb];
            bl[j] = *(const f16x8*)&BlL[Rb * 32 + sb];
        }
#pragma unroll
        for (int i = 0; i < 4; ++i) {
            const int Ra = (wr << 6) + (i << 4) + lr;
            const int sa = ((lk ^ ((Ra >> 1) & 3)) << 3);
            const f16x8 ah = *(const f16x8*)&AhL[Ra * 32 + sa];
            const f16x8 al = *(const f16x8*)&AlL[Ra * 32 + sa];
#pragma unroll
            for (int j = 0; j < 4; ++j) {
                acc1[i][j] = __builtin_amdgcn_mfma_f32_16x16x32_f16(ah, bh[j], acc1[i][j], 0, 0, 0);
                acc2[i][j] = __builtin_amdgcn_mfma_f32_16x16x32_f16(al, bh[j], acc2[i][j], 0, 0, 0);
                acc2[i][j] = __builtin_amdgcn_mfma_f32_16x16x32_f16(ah, bl[j], acc2[i][j], 0, 0, 0);
            }
        }
    }

    // C/D layout: col = lane&15, row = (lane>>4)*4 + reg
#pragma unroll
    for (int j = 0; j < 4; ++j) {
        const int col = n0 + (wc << 6) + (j << 4) + lr;
        const float bv = bias[col];
#pragma unroll
        for (int i = 0; i < 4; ++i) {
#pragma unroll
            for (int r = 0; r < 4; ++r) {
                const int row = m0 + (wr << 6) + (i << 4) + (lk << 2) + r;
                const float val = acc1[i][j][r] + acc2[i][j][r] * (1.0f / 2048.0f) + bv;
                f16 h, l;
                split_hl(val, h, l);
                size_t addr;
                if (z != 2)  // Q, K: [b, h, s, d]
                    addr = (((size_t)(row >> 11) * NHEADS + (col >> 6)) * SEQ +
                            (row & (SEQ - 1))) * HDIM + (col & (HDIM - 1));
                else         // V: [b, h, d, s]
                    addr = (((size_t)(row >> 11) * NHEADS + (col >> 6)) * HDIM +
                            (col & (HDIM - 1))) * SEQ + (row & (SEQ - 1));
                OH[addr] = h;
                OL[addr] = l;
            }
        }
    }
}

// ---------------------------------------------------------------------------
// O-projection hi/lo fp16 MFMA GEMM-NT, f32 C + residual epilogue.
// Same global_load_lds staging as gemm_qkv.
// ---------------------------------------------------------------------------
__global__ __launch_bounds__(256, 2) void gemm_oproj(const f16* __restrict__ Ah_g,
                                                     const f16* __restrict__ Al_g,
                                                     const f16* __restrict__ Bh_g,
                                                     const f16* __restrict__ Bl_g,
                                                     const float* __restrict__ bias,
                                                     const float* __restrict__ R,
                                                     float* __restrict__ C) {
    constexpr int K = HIDDEN, N = HIDDEN;
    __shared__ __align__(16) f16 AhL[128 * 32], AlL[128 * 32];
    __shared__ __align__(16) f16 BhL[128 * 32], BlL[128 * 32];
    const int tid = threadIdx.x;
    const int m0 = blockIdx.x << 7, n0 = blockIdx.y << 7;
    const int w = tid >> 6, lane = tid & 63;
    const int wr = w >> 1, wc = w & 1;
    const int lr = lane & 15, lk = lane >> 4;
    const f16* sg = (w == 0) ? Ah_g : (w == 1) ? Al_g : (w == 2) ? Bh_g : Bl_g;
    f16* sd = (w == 0) ? AhL : (w == 1) ? AlL : (w == 2) ? BhL : BlL;
    const int t0 = (w < 2) ? m0 : n0;
    const int srow = lane >> 2;
    const int sslot = lane & 3;
    const f32x4 zf = {0.f, 0.f, 0.f, 0.f};
    f32x4 acc1[4][4], acc2[4][4];
#pragma unroll
    for (int i = 0; i < 4; ++i)
#pragma unroll
        for (int j = 0; j < 4; ++j) { acc1[i][j] = zf; acc2[i][j] = zf; }

    for (int k0 = 0; k0 < K; k0 += 32) {
        __syncthreads();
#pragma unroll
        for (int q = 0; q < 8; ++q) {
            const int r = (q << 4) + srow;
            const int g = sslot ^ ((r >> 1) & 3);
            gload16(sg + (size_t)(t0 + r) * K + k0 + (g << 3), sd + (q << 9));
        }
        __syncthreads();
        f16x8 bh[4], bl[4];
#pragma unroll
        for (int j = 0; j < 4; ++j) {
            const int Rb = (wc << 6) + (j << 4) + lr;
            const int sb = ((lk ^ ((Rb >> 1) & 3)) << 3);
            bh[j] = *(const f16x8*)&BhL[Rb * 32 + sb];
            bl[j] = *(const f16x8*)&BlL[Rb * 32 + sb];
        }
#pragma unroll
        for (int i = 0; i < 4; ++i) {
            const int Ra = (wr << 6) + (i << 4) + lr;
            const int sa = ((lk ^ ((Ra >> 1) & 3)) << 3);
            const f16x8 ah = *(const f16x8*)&AhL[Ra * 32 + sa];
            const f16x8 al = *(const f16x8*)&AlL[Ra * 32 + sa];
#pragma unroll
            for (int j = 0; j < 4; ++j) {
                acc1[i][j] = __builtin_amdgcn_mfma_f32_16x16x32_f16(ah, bh[j], acc1[i][j], 0, 0, 0);
                acc2[i][j] = __builtin_amdgcn_mfma_f32_16x16x32_f16(al, bh[j], acc2[i][j], 0, 0, 0);
                acc2[i][j] = __builtin_amdgcn_mfma_f32_16x16x32_f16(ah, bl[j], acc2[i][j], 0, 0, 0);
            }
        }
    }

#pragma unroll
    for (int j = 0; j < 4; ++j) {
        const int col = n0 + (wc << 6) + (j << 4) + lr;
        const float bv = bias[col];
#pragma unroll
        for (int i = 0; i < 4; ++i) {
#pragma unroll
            for (int r = 0; r < 4; ++r) {
                const int row = m0 + (wr << 6) + (i << 4) + (lk << 2) + r;
                float val = acc1[i][j][r] + acc2[i][j][r] * (1.0f / 2048.0f) + bv;
                val += R[(size_t)row * N + col];
                C[(size_t)row * N + col] = val;
            }
        }
    }
}

// ---------------------------------------------------------------------------
// MFMA flash attention, causal sliding window 256. (unchanged, verified)
// ---------------------------------------------------------------------------
#define QT 128
__global__ __launch_bounds__(256, 2) void attn_mfma(const f16* __restrict__ Qh,
                                                    const f16* __restrict__ Ql,
                                                    const f16* __restrict__ Kh,
                                                    const f16* __restrict__ Kl,
                                                    const f16* __restrict__ Vh,
                                                    f16* __restrict__ Oh,
                                                    f16* __restrict__ Ol) {
    __shared__ f16 Ks_h[64][72];   // [k][d], pad->72 => 8 lanes/bank-quad (b128 optimum)
    __shared__ f16 Ks_l[64][72];
    __shared__ f16 Vs[64][72];     // [d][k] (pre-transposed in global)
    __shared__ f16 Ps[4][32][72];  // per-wave P[qrow][k]
    const int qt = blockIdx.x, bh = blockIdx.y;
    const int q0 = qt * QT;
    const int tid = threadIdx.x;
    const int w = tid >> 6, lane = tid & 63;
    const int lr = lane & 15, lk = lane >> 4;
    const int qbase = q0 + w * 32;
    const float csc = 0.18033688011112042f;  // log2(e)/sqrt(64)

    f16x8 qh[2][2], ql[2][2];
#pragma unroll
    for (int qf = 0; qf < 2; ++qf)
#pragma unroll
        for (int g = 0; g < 2; ++g) {
            const size_t ga = ((size_t)bh * SEQ + qbase + qf * 16 + lr) * HDIM + g * 32 + lk * 8;
            qh[qf][g] = *(const f16x8*)(Qh + ga);
            ql[qf][g] = *(const f16x8*)(Ql + ga);
        }

    const f32x4 z = {0.f, 0.f, 0.f, 0.f};
    f32x4 o1[2][4];
    float m_[2][4], l_[2][4];
#pragma unroll
    for (int qf = 0; qf < 2; ++qf)
#pragma unroll
        for (int r = 0; r < 4; ++r) { m_[qf][r] = -1e30f; l_[qf][r] = 0.f; }
#pragma unroll
    for (int qf = 0; qf < 2; ++qf)
#pragma unroll
        for (int df = 0; df < 4; ++df) o1[qf][df] = z;

    const int kt0 = (q0 >> 6) - 4;
    for (int t = 0; t < 6; ++t) {
        const int kt = kt0 + t;
        if (kt < 0) continue;
        const int k0 = kt << 6;
        __syncthreads();
#pragma unroll
        for (int rep = 0; rep < 2; ++rep) {
            const int idx = rep * 256 + tid;
            const int r = idx >> 3, sg = (idx & 7) << 3;
            const size_t gk = ((size_t)bh * SEQ + k0 + r) * HDIM + sg;
            *(f16x8*)&Ks_h[r][sg] = *(const f16x8*)(Kh + gk);
            *(f16x8*)&Ks_l[r][sg] = *(const f16x8*)(Kl + gk);
            const size_t gv = ((size_t)bh * HDIM + r) * SEQ + k0 + sg;
            *(f16x8*)&Vs[r][sg] = *(const f16x8*)(Vh + gv);
        }
        __syncthreads();

        f32x4 s1[2][4], s2[2][4];
#pragma unroll
        for (int qf = 0; qf < 2; ++qf)
#pragma unroll
            for (int kf = 0; kf < 4; ++kf) { s1[qf][kf] = z; s2[qf][kf] = z; }
#pragma unroll
        for (int g = 0; g < 2; ++g)
#pragma unroll
            for (int kf = 0; kf < 4; ++kf) {
                const f16x8 kbh = *(const f16x8*)&Ks_h[kf * 16 + lr][g * 32 + lk * 8];
                const f16x8 kbl = *(const f16x8*)&Ks_l[kf * 16 + lr][g * 32 + lk * 8];
#pragma unroll
                for (int qf = 0; qf < 2; ++qf) {
                    s1[qf][kf] = __builtin_amdgcn_mfma_f32_16x16x32_f16(qh[qf][g], kbh, s1[qf][kf], 0, 0, 0);
                    s2[qf][kf] = __builtin_amdgcn_mfma_f32_16x16x32_f16(ql[qf][g], kbh, s2[qf][kf], 0, 0, 0);
                    s2[qf][kf] = __builtin_amdgcn_mfma_f32_16x16x32_f16(qh[qf][g], kbl, s2[qf][kf], 0, 0, 0);
                }
            }

#pragma unroll
        for (int qf = 0; qf < 2; ++qf) {
#pragma unroll
            for (int r = 0; r < 4; ++r) {
                const int qg = qbase + qf * 16 + lk * 4 + r;
                float sc[4];
                bool ok[4];
                float rm = -1e30f;
#pragma unroll
                for (int kf = 0; kf < 4; ++kf) {
                    const int kg = k0 + kf * 16 + lr;
                    sc[kf] = s1[qf][kf][r] + s2[qf][kf][r] * (1.0f / 2048.0f);
                    ok[kf] = (kg <= qg) && (kg + WINDOW > qg);
                    if (!ok[kf]) sc[kf] = -1e30f;
                    rm = fmaxf(rm, sc[kf]);
                }
                rm = fmaxf(rm, __shfl_xor(rm, 1));
                rm = fmaxf(rm, __shfl_xor(rm, 2));
                rm = fmaxf(rm, __shfl_xor(rm, 4));
                rm = fmaxf(rm, __shfl_xor(rm, 8));
                const float mnew = fmaxf(m_[qf][r], rm);
                const float corr = exp2f((m_[qf][r] - mnew) * csc);
                float rs = 0.f;
#pragma unroll
                for (int kf = 0; kf < 4; ++kf) {
                    const float p = ok[kf] ? exp2f((sc[kf] - mnew) * csc) : 0.f;
                    sc[kf] = p;
                    rs += p;
                }
                rs += __shfl_xor(rs, 1);
                rs += __shfl_xor(rs, 2);
                rs += __shfl_xor(rs, 4);
                rs += __shfl_xor(rs, 8);
                l_[qf][r] = l_[qf][r] * corr + rs;
                m_[qf][r] = mnew;
#pragma unroll
                for (int df = 0; df < 4; ++df) o1[qf][df][r] *= corr;
#pragma unroll
                for (int kf = 0; kf < 4; ++kf)
                    Ps[w][qf * 16 + lk * 4 + r][kf * 16 + lr] = (f16)sc[kf];
            }
        }
        // Ps is wave-private: no __syncthreads needed before PV.

#pragma unroll
        for (int g = 0; g < 2; ++g) {
            f16x8 pa[2];
#pragma unroll
            for (int qf = 0; qf < 2; ++qf)
                pa[qf] = *(const f16x8*)&Ps[w][qf * 16 + lr][g * 32 + lk * 8];
#pragma unroll
            for (int df = 0; df < 4; ++df) {
                const f16x8 vb = *(const f16x8*)&Vs[df * 16 + lr][g * 32 + lk * 8];
#pragma unroll
                for (int qf = 0; qf < 2; ++qf)
                    o1[qf][df] = __builtin_amdgcn_mfma_f32_16x16x32_f16(pa[qf], vb, o1[qf][df], 0, 0, 0);
            }
        }
    }

    const int b = bh >> 4, h = bh & 15;
#pragma unroll
    for (int qf = 0; qf < 2; ++qf) {
#pragma unroll
        for (int r = 0; r < 4; ++r) {
            const float inv = 1.f / l_[qf][r];
            const size_t mrow = (size_t)b * SEQ + qbase + qf * 16 + lk * 4 + r;
#pragma unroll
            for (int df = 0; df < 4; ++df) {
                const int col = h * HDIM + df * 16 + lr;
                f16 hh, ll;
                split_hl(o1[qf][df][r] * inv, hh, ll);
                Oh[mrow * HIDDEN + col] = hh;
                Ol[mrow * HIDDEN + col] = ll;
            }
        }
    }
}

// ---------------------------------------------------------------------------
extern "C" void kernel_launch(void* const* d_in, const int* in_sizes, int n_in,
                              void* d_out, int out_size, void* d_ws, size_t ws_size,
                              hipStream_t stream) {
    const float* hs    = (const float*)d_in[0];
    const float* gamma = (const float*)d_in[1];
    const float* beta  = (const float*)d_in[2];
    const float* Wq    = (const float*)d_in[3];
    const float* bq    = (const float*)d_in[4];
    const float* Wk    = (const float*)d_in[5];
    const float* bk    = (const float*)d_in[6];
    const float* Wv    = (const float*)d_in[7];
    const float* bv    = (const float*)d_in[8];
    const float* Wo    = (const float*)d_in[9];
    const float* bo    = (const float*)d_in[10];
    float* out = (float*)d_out;

    const size_t NTOK = (size_t)MTOK * HIDDEN;   // 4M elems
    const size_t NW = (size_t)HIDDEN * HIDDEN;   // 1M elems per weight
    char* p = (char*)d_ws;
    f16* xhi = (f16*)p;  p += NTOK * sizeof(f16);
    f16* xlo = (f16*)p;  p += NTOK * sizeof(f16);
    f16* wqh = (f16*)p;  p += NW * sizeof(f16);
    f16* wql = (f16*)p;  p += NW * sizeof(f16);
    f16* wkh = (f16*)p;  p += NW * sizeof(f16);
    f16* wkl = (f16*)p;  p += NW * sizeof(f16);
    f16* wvh = (f16*)p;  p += NW * sizeof(f16);
    f16* wvl = (f16*)p;  p += NW * sizeof(f16);
    f16* woh = (f16*)p;  p += NW * sizeof(f16);
    f16* wol = (f16*)p;  p += NW * sizeof(f16);
    f16* Qh  = (f16*)p;  p += NTOK * sizeof(f16);
    f16* Ql  = (f16*)p;  p += NTOK * sizeof(f16);
    f16* Kh  = (f16*)p;  p += NTOK * sizeof(f16);
    f16* Kl  = (f16*)p;  p += NTOK * sizeof(f16);
    f16* Vh  = (f16*)p;  p += NTOK * sizeof(f16);
    f16* Vl  = (f16*)p;  p += NTOK * sizeof(f16);
    f16* ohi = (f16*)p;  p += NTOK * sizeof(f16);
    f16* olo = (f16*)p;  p += NTOK * sizeof(f16);

    hipLaunchKernelGGL(ln_split_kernel, dim3(MTOK), dim3(256), 0, stream,
                       hs, gamma, beta, xhi, xlo);

    hipLaunchKernelGGL(wsplit_kernel, dim3((int)(NW / 8 / 256), 4), dim3(256), 0, stream,
                       Wq, Wk, Wv, Wo, wqh, wql, wkh, wkl, wvh, wvl, woh, wol);

    // Fused Q/K/V projections: grid.z selects output; 768 blocks = 3/CU.
    hipLaunchKernelGGL(gemm_qkv, dim3(MTOK / 128, HIDDEN / 128, 3), dim3(256), 0, stream,
                       xhi, xlo, wqh, wql, wkh, wkl, wvh, wvl, bq, bk, bv,
                       Qh, Ql, Kh, Kl, Vh, Vl);

    hipLaunchKernelGGL(attn_mfma, dim3(SEQ / QT, BATCH * NHEADS), dim3(256), 0, stream,
                       Qh, Ql, Kh, Kl, Vh, ohi, olo);

    hipLaunchKernelGGL(gemm_oproj, dim3(MTOK / 128, HIDDEN / 128), dim3(256), 0, stream,
                       ohi, olo, woh, wol, bo, hs, out);
}

// Round 11
// 197.808 us; speedup vs baseline: 1.4820x; 1.4820x over previous
//
#include <hip/hip_runtime.h>

#define HIDDEN 1024
#define NHEADS 16
#define HDIM 64
#define WINDOW 256
#define SEQ 2048
#define BATCH 2
#define MTOK (BATCH * SEQ)
#define LN_EPS 1e-12f

typedef _Float16 f16;
typedef _Float16 f16x4 __attribute__((ext_vector_type(4)));
typedef _Float16 f16x8 __attribute__((ext_vector_type(8)));
typedef float f32x4 __attribute__((ext_vector_type(4)));

// PRECISION EXPERIMENT (this round): plain f16 inputs, fp32 MFMA accum —
// hi/lo correction dropped. Evidence: absmax bit-identical 0.015625 across
// fp32 and f16-hi/lo paths => floor is reference-side; our added ~3e-3
// should keep absmax ~0.016-0.018. Fallback = round-10 3-pass kernel.

// Direct global->LDS 16B async copy. LDS dest is WAVE-UNIFORM base; HW writes
// lane i's 16B at dest + i*16 (m104). Global src addr is per-lane (m173).
__device__ __forceinline__ void gload16(const f16* g, f16* l) {
    __builtin_amdgcn_global_load_lds(
        (const __attribute__((address_space(1))) void*)g,
        (__attribute__((address_space(3))) void*)l, 16, 0, 0);
}

// ---------------------------------------------------------------------------
// LayerNorm fused with f16 cast. One block per token row.
// ---------------------------------------------------------------------------
__global__ __launch_bounds__(256) void ln_cast_kernel(const float* __restrict__ X,
                                                      const float* __restrict__ g,
                                                      const float* __restrict__ be,
                                                      f16* __restrict__ XH) {
    const int row = blockIdx.x;
    const int t = threadIdx.x;
    const float4 v = ((const float4*)(X + (size_t)row * HIDDEN))[t];
    float s = v.x + v.y + v.z + v.w;
    float s2 = v.x * v.x + v.y * v.y + v.z * v.z + v.w * v.w;
#pragma unroll
    for (int off = 1; off < 64; off <<= 1) {
        s += __shfl_xor(s, off);
        s2 += __shfl_xor(s2, off);
    }
    __shared__ float ss[4], ss2[4];
    if ((t & 63) == 0) { ss[t >> 6] = s; ss2[t >> 6] = s2; }
    __syncthreads();
    s = ss[0] + ss[1] + ss[2] + ss[3];
    s2 = ss2[0] + ss2[1] + ss2[2] + ss2[3];
    const float mu = s * (1.f / HIDDEN);
    const float var = s2 * (1.f / HIDDEN) - mu * mu;
    const float rstd = rsqrtf(var + LN_EPS);
    const float4 gv = ((const float4*)g)[t];
    const float4 bv = ((const float4*)be)[t];
    f16x4 h;
    h[0] = (f16)((v.x - mu) * rstd * gv.x + bv.x);
    h[1] = (f16)((v.y - mu) * rstd * gv.y + bv.y);
    h[2] = (f16)((v.z - mu) * rstd * gv.z + bv.z);
    h[3] = (f16)((v.w - mu) * rstd * gv.w + bv.w);
    ((f16x4*)(XH + (size_t)row * HIDDEN))[t] = h;
}

// ---------------------------------------------------------------------------
// All-4-weights f32 -> f16 cast in one launch (blockIdx.y = tensor).
// ---------------------------------------------------------------------------
__global__ __launch_bounds__(256) void wcast_kernel(const float* __restrict__ W0,
                                                    const float* __restrict__ W1,
                                                    const float* __restrict__ W2,
                                                    const float* __restrict__ W3,
                                                    f16* __restrict__ H0,
                                                    f16* __restrict__ H1,
                                                    f16* __restrict__ H2,
                                                    f16* __restrict__ H3) {
    const float* X = (blockIdx.y == 0) ? W0 : (blockIdx.y == 1) ? W1 : (blockIdx.y == 2) ? W2 : W3;
    f16* H = (blockIdx.y == 0) ? H0 : (blockIdx.y == 1) ? H1 : (blockIdx.y == 2) ? H2 : H3;
    const int i = blockIdx.x * 256 + threadIdx.x;  // 8 elems per thread
    const float4 a = ((const float4*)X)[2 * i];
    const float4 b = ((const float4*)X)[2 * i + 1];
    f16x8 h;
    h[0] = (f16)a.x; h[1] = (f16)a.y; h[2] = (f16)a.z; h[3] = (f16)a.w;
    h[4] = (f16)b.x; h[5] = (f16)b.y; h[6] = (f16)b.z; h[7] = (f16)b.w;
    ((f16x8*)H)[i] = h;
}

// ---------------------------------------------------------------------------
// Staging (verified round 10): global_load_lds width-16, linear [128][32]
// LDS rows with XOR swizzle slot'=slot^((row>>1)&3) on BOTH sides — measured
// SQ_LDS_BANK_CONFLICT = 0. Now 2 arrays (Ah,Bh): waves {0,1} stage A
// (chunks 0-3 / 4-7), waves {2,3} stage B. 4 gload16 per wave per K-step.
// ---------------------------------------------------------------------------

// ---------------------------------------------------------------------------
// FUSED Q/K/V f16 MFMA GEMM-NT, 1-pass. blockIdx.z selects weight/bias/out
// (Q, K -> [b,h,s,d]; V -> [b,h,d,s]). acc = 64 VGPR -> 3 waves/SIMD.
// ---------------------------------------------------------------------------
__global__ __launch_bounds__(256, 3) void gemm_qkv(
        const f16* __restrict__ A_g,
        const f16* __restrict__ W0, const f16* __restrict__ W1,
        const f16* __restrict__ W2,
        const float* __restrict__ b0, const float* __restrict__ b1,
        const float* __restrict__ b2,
        f16* __restrict__ O0, f16* __restrict__ O1, f16* __restrict__ O2) {
    constexpr int K = HIDDEN;
    __shared__ __align__(16) f16 AhL[128 * 32], BhL[128 * 32];
    const int z = blockIdx.z;  // uniform across block
    const f16* __restrict__ B_g = (z == 0) ? W0 : (z == 1) ? W1 : W2;
    const float* __restrict__ bias = (z == 0) ? b0 : (z == 1) ? b1 : b2;
    f16* __restrict__ OH = (z == 0) ? O0 : (z == 1) ? O1 : O2;
    const int tid = threadIdx.x;
    const int m0 = blockIdx.x << 7, n0 = blockIdx.y << 7;
    const int w = tid >> 6, lane = tid & 63;
    const int wr = w >> 1, wc = w & 1;            // wave grid 2x2
    const int lr = lane & 15, lk = lane >> 4;     // frag row + k-group
    // staging role: waves 0,1 -> A (chunk halves), waves 2,3 -> B
    const f16* sg = (w < 2) ? A_g : B_g;
    f16* sd = (w < 2) ? AhL : BhL;
    const int t0 = (w < 2) ? m0 : n0;
    const int qb = (w & 1) << 2;                  // chunks 0-3 or 4-7
    const int srow = lane >> 2;                   // row within 16-row chunk
    const int sslot = lane & 3;                   // 16B slot within 64B row
    const f32x4 zf = {0.f, 0.f, 0.f, 0.f};
    f32x4 acc[4][4];
#pragma unroll
    for (int i = 0; i < 4; ++i)
#pragma unroll
        for (int j = 0; j < 4; ++j) acc[i][j] = zf;

    for (int k0 = 0; k0 < K; k0 += 32) {
        __syncthreads();
#pragma unroll
        for (int q = 0; q < 4; ++q) {
            const int qq = qb + q;
            const int r = (qq << 4) + srow;                // tile row 0..127
            const int g = sslot ^ ((r >> 1) & 3);          // inverse swizzle on src
            gload16(sg + (size_t)(t0 + r) * K + k0 + (g << 3), sd + (qq << 9));
        }
        __syncthreads();
        f16x8 bh[4];
#pragma unroll
        for (int j = 0; j < 4; ++j) {
            const int Rb = (wc << 6) + (j << 4) + lr;
            bh[j] = *(const f16x8*)&BhL[Rb * 32 + ((lk ^ ((Rb >> 1) & 3)) << 3)];
        }
#pragma unroll
        for (int i = 0; i < 4; ++i) {
            const int Ra = (wr << 6) + (i << 4) + lr;
            const f16x8 ah = *(const f16x8*)&AhL[Ra * 32 + ((lk ^ ((Ra >> 1) & 3)) << 3)];
#pragma unroll
            for (int j = 0; j < 4; ++j)
                acc[i][j] = __builtin_amdgcn_mfma_f32_16x16x32_f16(ah, bh[j], acc[i][j], 0, 0, 0);
        }
    }

    // C/D layout: col = lane&15, row = (lane>>4)*4 + reg
#pragma unroll
    for (int j = 0; j < 4; ++j) {
        const int col = n0 + (wc << 6) + (j << 4) + lr;
        const float bv = bias[col];
#pragma unroll
        for (int i = 0; i < 4; ++i) {
#pragma unroll
            for (int r = 0; r < 4; ++r) {
                const int row = m0 + (wr << 6) + (i << 4) + (lk << 2) + r;
                const f16 h = (f16)(acc[i][j][r] + bv);
                size_t addr;
                if (z != 2)  // Q, K: [b, h, s, d]
                    addr = (((size_t)(row >> 11) * NHEADS + (col >> 6)) * SEQ +
                            (row & (SEQ - 1))) * HDIM + (col & (HDIM - 1));
                else         // V: [b, h, d, s]
                    addr = (((size_t)(row >> 11) * NHEADS + (col >> 6)) * HDIM +
                            (col & (HDIM - 1))) * SEQ + (row & (SEQ - 1));
                OH[addr] = h;
            }
        }
    }
}

// ---------------------------------------------------------------------------
// O-projection f16 MFMA GEMM-NT, 1-pass, f32 C + residual epilogue.
// ---------------------------------------------------------------------------
__global__ __launch_bounds__(256, 3) void gemm_oproj(const f16* __restrict__ A_g,
                                                     const f16* __restrict__ B_g,
                                                     const float* __restrict__ bias,
                                                     const float* __restrict__ R,
                                                     float* __restrict__ C) {
    constexpr int K = HIDDEN, N = HIDDEN;
    __shared__ __align__(16) f16 AhL[128 * 32], BhL[128 * 32];
    const int tid = threadIdx.x;
    const int m0 = blockIdx.x << 7, n0 = blockIdx.y << 7;
    const int w = tid >> 6, lane = tid & 63;
    const int wr = w >> 1, wc = w & 1;
    const int lr = lane & 15, lk = lane >> 4;
    const f16* sg = (w < 2) ? A_g : B_g;
    f16* sd = (w < 2) ? AhL : BhL;
    const int t0 = (w < 2) ? m0 : n0;
    const int qb = (w & 1) << 2;
    const int srow = lane >> 2;
    const int sslot = lane & 3;
    const f32x4 zf = {0.f, 0.f, 0.f, 0.f};
    f32x4 acc[4][4];
#pragma unroll
    for (int i = 0; i < 4; ++i)
#pragma unroll
        for (int j = 0; j < 4; ++j) acc[i][j] = zf;

    for (int k0 = 0; k0 < K; k0 += 32) {
        __syncthreads();
#pragma unroll
        for (int q = 0; q < 4; ++q) {
            const int qq = qb + q;
            const int r = (qq << 4) + srow;
            const int g = sslot ^ ((r >> 1) & 3);
            gload16(sg + (size_t)(t0 + r) * K + k0 + (g << 3), sd + (qq << 9));
        }
        __syncthreads();
        f16x8 bh[4];
#pragma unroll
        for (int j = 0; j < 4; ++j) {
            const int Rb = (wc << 6) + (j << 4) + lr;
            bh[j] = *(const f16x8*)&BhL[Rb * 32 + ((lk ^ ((Rb >> 1) & 3)) << 3)];
        }
#pragma unroll
        for (int i = 0; i < 4; ++i) {
            const int Ra = (wr << 6) + (i << 4) + lr;
            const f16x8 ah = *(const f16x8*)&AhL[Ra * 32 + ((lk ^ ((Ra >> 1) & 3)) << 3)];
#pragma unroll
            for (int j = 0; j < 4; ++j)
                acc[i][j] = __builtin_amdgcn_mfma_f32_16x16x32_f16(ah, bh[j], acc[i][j], 0, 0, 0);
        }
    }

#pragma unroll
    for (int j = 0; j < 4; ++j) {
        const int col = n0 + (wc << 6) + (j << 4) + lr;
        const float bv = bias[col];
#pragma unroll
        for (int i = 0; i < 4; ++i) {
#pragma unroll
            for (int r = 0; r < 4; ++r) {
                const int row = m0 + (wr << 6) + (i << 4) + (lk << 2) + r;
                C[(size_t)row * N + col] = acc[i][j][r] + bv + R[(size_t)row * N + col];
            }
        }
    }
}

// ---------------------------------------------------------------------------
// MFMA flash attention, causal sliding window 256. Plain f16 Q,K,V (1-pass
// QK^T); structure otherwise identical to the verified round-10 kernel.
// LDS 36 KB.
// ---------------------------------------------------------------------------
#define QT 128
__global__ __launch_bounds__(256, 2) void attn_mfma(const f16* __restrict__ Qh,
                                                    const f16* __restrict__ Kh,
                                                    const f16* __restrict__ Vh,
                                                    f16* __restrict__ Oh) {
    __shared__ f16 Ks[64][72];     // [k][d], pad->72 (verified conflict-light)
    __shared__ f16 Vs[64][72];     // [d][k] (pre-transposed in global)
    __shared__ f16 Ps[4][32][72];  // per-wave P[qrow][k]
    const int qt = blockIdx.x, bh = blockIdx.y;
    const int q0 = qt * QT;
    const int tid = threadIdx.x;
    const int w = tid >> 6, lane = tid & 63;
    const int lr = lane & 15, lk = lane >> 4;
    const int qbase = q0 + w * 32;
    const float csc = 0.18033688011112042f;  // log2(e)/sqrt(64)

    f16x8 qh[2][2];
#pragma unroll
    for (int qf = 0; qf < 2; ++qf)
#pragma unroll
        for (int g = 0; g < 2; ++g) {
            const size_t ga = ((size_t)bh * SEQ + qbase + qf * 16 + lr) * HDIM + g * 32 + lk * 8;
            qh[qf][g] = *(const f16x8*)(Qh + ga);
        }

    const f32x4 z = {0.f, 0.f, 0.f, 0.f};
    f32x4 o1[2][4];
    float m_[2][4], l_[2][4];
#pragma unroll
    for (int qf = 0; qf < 2; ++qf)
#pragma unroll
        for (int r = 0; r < 4; ++r) { m_[qf][r] = -1e30f; l_[qf][r] = 0.f; }
#pragma unroll
    for (int qf = 0; qf < 2; ++qf)
#pragma unroll
        for (int df = 0; df < 4; ++df) o1[qf][df] = z;

    const int kt0 = (q0 >> 6) - 4;
    for (int t = 0; t < 6; ++t) {
        const int kt = kt0 + t;
        if (kt < 0) continue;
        const int k0 = kt << 6;
        __syncthreads();
#pragma unroll
        for (int rep = 0; rep < 2; ++rep) {
            const int idx = rep * 256 + tid;
            const int r = idx >> 3, sg = (idx & 7) << 3;
            const size_t gk = ((size_t)bh * SEQ + k0 + r) * HDIM + sg;
            *(f16x8*)&Ks[r][sg] = *(const f16x8*)(Kh + gk);
            const size_t gv = ((size_t)bh * HDIM + r) * SEQ + k0 + sg;
            *(f16x8*)&Vs[r][sg] = *(const f16x8*)(Vh + gv);
        }
        __syncthreads();

        f32x4 s1[2][4];
#pragma unroll
        for (int qf = 0; qf < 2; ++qf)
#pragma unroll
            for (int kf = 0; kf < 4; ++kf) s1[qf][kf] = z;
#pragma unroll
        for (int g = 0; g < 2; ++g)
#pragma unroll
            for (int kf = 0; kf < 4; ++kf) {
                const f16x8 kb = *(const f16x8*)&Ks[kf * 16 + lr][g * 32 + lk * 8];
#pragma unroll
                for (int qf = 0; qf < 2; ++qf)
                    s1[qf][kf] = __builtin_amdgcn_mfma_f32_16x16x32_f16(qh[qf][g], kb, s1[qf][kf], 0, 0, 0);
            }

#pragma unroll
        for (int qf = 0; qf < 2; ++qf) {
#pragma unroll
            for (int r = 0; r < 4; ++r) {
                const int qg = qbase + qf * 16 + lk * 4 + r;
                float sc[4];
                bool ok[4];
                float rm = -1e30f;
#pragma unroll
                for (int kf = 0; kf < 4; ++kf) {
                    const int kg = k0 + kf * 16 + lr;
                    sc[kf] = s1[qf][kf][r];
                    ok[kf] = (kg <= qg) && (kg + WINDOW > qg);
                    if (!ok[kf]) sc[kf] = -1e30f;
                    rm = fmaxf(rm, sc[kf]);
                }
                rm = fmaxf(rm, __shfl_xor(rm, 1));
                rm = fmaxf(rm, __shfl_xor(rm, 2));
                rm = fmaxf(rm, __shfl_xor(rm, 4));
                rm = fmaxf(rm, __shfl_xor(rm, 8));
                const float mnew = fmaxf(m_[qf][r], rm);
                const float corr = exp2f((m_[qf][r] - mnew) * csc);
                float rs = 0.f;
#pragma unroll
                for (int kf = 0; kf < 4; ++kf) {
                    const float p = ok[kf] ? exp2f((sc[kf] - mnew) * csc) : 0.f;
                    sc[kf] = p;
                    rs += p;
                }
                rs += __shfl_xor(rs, 1);
                rs += __shfl_xor(rs, 2);
                rs += __shfl_xor(rs, 4);
                rs += __shfl_xor(rs, 8);
                l_[qf][r] = l_[qf][r] * corr + rs;
                m_[qf][r] = mnew;
#pragma unroll
                for (int df = 0; df < 4; ++df) o1[qf][df][r] *= corr;
#pragma unroll
                for (int kf = 0; kf < 4; ++kf)
                    Ps[w][qf * 16 + lk * 4 + r][kf * 16 + lr] = (f16)sc[kf];
            }
        }
        // Ps is wave-private: no __syncthreads needed before PV.

#pragma unroll
        for (int g = 0; g < 2; ++g) {
            f16x8 pa[2];
#pragma unroll
            for (int qf = 0; qf < 2; ++qf)
                pa[qf] = *(const f16x8*)&Ps[w][qf * 16 + lr][g * 32 + lk * 8];
#pragma unroll
            for (int df = 0; df < 4; ++df) {
                const f16x8 vb = *(const f16x8*)&Vs[df * 16 + lr][g * 32 + lk * 8];
#pragma unroll
                for (int qf = 0; qf < 2; ++qf)
                    o1[qf][df] = __builtin_amdgcn_mfma_f32_16x16x32_f16(pa[qf], vb, o1[qf][df], 0, 0, 0);
            }
        }
    }

    const int b = bh >> 4, h = bh & 15;
#pragma unroll
    for (int qf = 0; qf < 2; ++qf) {
#pragma unroll
        for (int r = 0; r < 4; ++r) {
            const float inv = 1.f / l_[qf][r];
            const size_t mrow = (size_t)b * SEQ + qbase + qf * 16 + lk * 4 + r;
#pragma unroll
            for (int df = 0; df < 4; ++df) {
                const int col = h * HDIM + df * 16 + lr;
                Oh[mrow * HIDDEN + col] = (f16)(o1[qf][df][r] * inv);
            }
        }
    }
}

// ---------------------------------------------------------------------------
extern "C" void kernel_launch(void* const* d_in, const int* in_sizes, int n_in,
                              void* d_out, int out_size, void* d_ws, size_t ws_size,
                              hipStream_t stream) {
    const float* hs    = (const float*)d_in[0];
    const float* gamma = (const float*)d_in[1];
    const float* beta  = (const float*)d_in[2];
    const float* Wq    = (const float*)d_in[3];
    const float* bq    = (const float*)d_in[4];
    const float* Wk    = (const float*)d_in[5];
    const float* bk    = (const float*)d_in[6];
    const float* Wv    = (const float*)d_in[7];
    const float* bv    = (const float*)d_in[8];
    const float* Wo    = (const float*)d_in[9];
    const float* bo    = (const float*)d_in[10];
    float* out = (float*)d_out;

    const size_t NTOK = (size_t)MTOK * HIDDEN;   // 4M elems
    const size_t NW = (size_t)HIDDEN * HIDDEN;   // 1M elems per weight
    char* p = (char*)d_ws;
    f16* xh  = (f16*)p;  p += NTOK * sizeof(f16);
    f16* wqh = (f16*)p;  p += NW * sizeof(f16);
    f16* wkh = (f16*)p;  p += NW * sizeof(f16);
    f16* wvh = (f16*)p;  p += NW * sizeof(f16);
    f16* woh = (f16*)p;  p += NW * sizeof(f16);
    f16* Qh  = (f16*)p;  p += NTOK * sizeof(f16);
    f16* Kh  = (f16*)p;  p += NTOK * sizeof(f16);
    f16* Vh  = (f16*)p;  p += NTOK * sizeof(f16);
    f16* oh  = (f16*)p;  p += NTOK * sizeof(f16);

    hipLaunchKernelGGL(ln_cast_kernel, dim3(MTOK), dim3(256), 0, stream,
                       hs, gamma, beta, xh);

    hipLaunchKernelGGL(wcast_kernel, dim3((int)(NW / 8 / 256), 4), dim3(256), 0, stream,
                       Wq, Wk, Wv, Wo, wqh, wkh, wvh, woh);

    // Fused Q/K/V projections: grid.z selects output; 768 blocks = 3/CU.
    hipLaunchKernelGGL(gemm_qkv, dim3(MTOK / 128, HIDDEN / 128, 3), dim3(256), 0, stream,
                       xh, wqh, wkh, wvh, bq, bk, bv, Qh, Kh, Vh);

    hipLaunchKernelGGL(attn_mfma, dim3(SEQ / QT, BATCH * NHEADS), dim3(256), 0, stream,
                       Qh, Kh, Vh, oh);

    hipLaunchKernelGGL(gemm_oproj, dim3(MTOK / 128, HIDDEN / 128), dim3(256), 0, stream,
                       oh, woh, bo, hs, out);
}